// Round 3
// baseline (779.802 us; speedup 1.0000x reference)
//
#include <hip/hip_runtime.h>
#include <cstddef>
#include <cstdint>

// ---------------------------------------------------------------------------
// GCN pipeline, restructured:
//   out = P @ A_hat @ (H1 @ W2) @ Wl + b2@Wl + bl          (no relu in layer 2)
//       = P @ A_hat @ (H1 @ U) + bb,     U = W2@Wl [512x8]
// so layer 2 GEMM + 512-wide aggregation + 512-wide pool collapse into an
// 8-column pipeline:
//   deg/dinv -> CSR -> convert x/W1 -> GEMM1(bf16 MFMA) -> AGG1(+relu) ->
//   U=W2@Wl -> Y=H1@U (MFMA, BN=16) -> mini-agg(8 cols) -> pool -> out
// ---------------------------------------------------------------------------

typedef unsigned short u16;
typedef short s16x8 __attribute__((ext_vector_type(8)));
typedef float f32x4 __attribute__((ext_vector_type(4)));

__device__ __forceinline__ float bf2f(u16 h) {
    union { unsigned int u; float f; } c; c.u = ((unsigned int)h) << 16; return c.f;
}
__device__ __forceinline__ u16 f2bf(float f) {
    union { float f; unsigned int u; } c; c.f = f;
    unsigned int u = c.u;
    u += 0x7FFFu + ((u >> 16) & 1u);   // round-to-nearest-even
    return (u16)(u >> 16);
}

#define GLD_LDS16(g, l) __builtin_amdgcn_global_load_lds( \
    (const __attribute__((address_space(1))) unsigned int*)(const void*)(g), \
    (__attribute__((address_space(3))) unsigned int*)(void*)(l), 16, 0, 0)

#define BM 128
#define BN 128
#define BKK 32

// ---------------------------------------------------------------------------
// bf16 MFMA GEMM: C[M,N]=A[M,K]@B[K,N]; Bt=B^T [N][K] bf16; C bf16.
// ---------------------------------------------------------------------------
__global__ __launch_bounds__(256) void gemm_bf16_kernel(
    const u16* __restrict__ A, const u16* __restrict__ Bt,
    u16* __restrict__ C, int M, int N, int K)
{
    __shared__ u16 As[BM * BKK];
    __shared__ u16 Bs[BN * BKK];
    const int tid = threadIdx.x;
    const int lane = tid & 63;
    const int wave = tid >> 6;
    const int wr = wave >> 1, wc = wave & 1;
    const int m0 = blockIdx.y * BM;
    const int n0 = blockIdx.x * BN;

    const int srow = tid >> 2;
    const int scol = (tid & 3) * 8;

    f32x4 acc[4][4] = {};

    const u16* aptr0 = A + (size_t)(m0 + srow) * K + scol;
    const u16* aptr1 = A + (size_t)(m0 + srow + 64) * K + scol;
    const u16* bptr0 = Bt + (size_t)(n0 + srow) * K + scol;
    const u16* bptr1 = Bt + (size_t)(n0 + srow + 64) * K + scol;

    for (int k0 = 0; k0 < K; k0 += BKK) {
        GLD_LDS16(aptr0 + k0, As + (size_t)tid * 8);
        GLD_LDS16(aptr1 + k0, As + (size_t)(256 + tid) * 8);
        GLD_LDS16(bptr0 + k0, Bs + (size_t)tid * 8);
        GLD_LDS16(bptr1 + k0, Bs + (size_t)(256 + tid) * 8);
        __syncthreads();

        s16x8 af[4], bfr[4];
#pragma unroll
        for (int mi = 0; mi < 4; ++mi)
            af[mi] = *(const s16x8*)(As + (wr * 64 + mi * 16 + (lane & 15)) * BKK + (lane >> 4) * 8);
#pragma unroll
        for (int nj = 0; nj < 4; ++nj)
            bfr[nj] = *(const s16x8*)(Bs + (wc * 64 + nj * 16 + (lane & 15)) * BKK + (lane >> 4) * 8);
#pragma unroll
        for (int mi = 0; mi < 4; ++mi)
#pragma unroll
            for (int nj = 0; nj < 4; ++nj)
                acc[mi][nj] = __builtin_amdgcn_mfma_f32_16x16x32_bf16(af[mi], bfr[nj], acc[mi][nj], 0, 0, 0);
        __syncthreads();
    }

    const int crow = (lane >> 4) * 4;
    const int ccol = lane & 15;
#pragma unroll
    for (int mi = 0; mi < 4; ++mi) {
        const int gr0 = m0 + wr * 64 + mi * 16 + crow;
#pragma unroll
        for (int r = 0; r < 4; ++r) {
            const int gr = gr0 + r;
            if (gr < M) {
#pragma unroll
                for (int nj = 0; nj < 4; ++nj)
                    C[(size_t)gr * N + n0 + wc * 64 + nj * 16 + ccol] = f2bf(acc[mi][nj][r]);
            }
        }
    }
}

// ---------------------------------------------------------------------------
// Y[M,8] = A[M,512] @ U[512,8] (fp32 out); Ut = U^T padded to [16][512] bf16.
// 128-row tile, 4 waves x 32 rows, BN=16 (cols 8..15 of Ut are zero).
// ---------------------------------------------------------------------------
__global__ __launch_bounds__(256) void gemmY_kernel(
    const u16* __restrict__ A, const u16* __restrict__ Ut,
    float* __restrict__ Y, int K)
{
    __shared__ u16 As[128 * 32];
    const int tid = threadIdx.x;
    const int lane = tid & 63;
    const int wave = tid >> 6;
    const int m0 = blockIdx.x * 128;
    const int srow = tid >> 2;
    const int scol = (tid & 3) * 8;

    f32x4 acc[2] = {};
    const u16* a0 = A + (size_t)(m0 + srow) * K + scol;
    const u16* a1 = A + (size_t)(m0 + 64 + srow) * K + scol;

    for (int k0 = 0; k0 < K; k0 += 32) {
        GLD_LDS16(a0 + k0, As + (size_t)tid * 8);
        GLD_LDS16(a1 + k0, As + (size_t)(256 + tid) * 8);
        s16x8 bfr = *(const s16x8*)(Ut + (size_t)(lane & 15) * K + k0 + (lane >> 4) * 8);
        __syncthreads();
        s16x8 af0 = *(const s16x8*)(As + (wave * 32 + (lane & 15)) * 32 + (lane >> 4) * 8);
        s16x8 af1 = *(const s16x8*)(As + (wave * 32 + 16 + (lane & 15)) * 32 + (lane >> 4) * 8);
        acc[0] = __builtin_amdgcn_mfma_f32_16x16x32_bf16(af0, bfr, acc[0], 0, 0, 0);
        acc[1] = __builtin_amdgcn_mfma_f32_16x16x32_bf16(af1, bfr, acc[1], 0, 0, 0);
        __syncthreads();
    }
    const int ccol = lane & 15;
    if (ccol < 8) {
        const int crow = (lane >> 4) * 4;
#pragma unroll
        for (int mi = 0; mi < 2; ++mi)
#pragma unroll
            for (int r = 0; r < 4; ++r)
                Y[(size_t)(m0 + wave * 32 + mi * 16 + crow + r) * 8 + ccol] = acc[mi][r];
    }
}

// ---------------------------------------------------------------------------
// setup kernels
// ---------------------------------------------------------------------------
__global__ void deg_cnt_kernel(const int* __restrict__ dst, const float* __restrict__ ew,
                               float* __restrict__ deg, int* __restrict__ cnt, int E)
{
    int e = blockIdx.x * blockDim.x + threadIdx.x;
    if (e >= E) return;
    int d = dst[e];
    atomicAdd(&deg[d], ew[e]);
    atomicAdd(&cnt[d], 1);
}

__global__ void dinv_kernel(float* __restrict__ deg, int Nn)
{
    int i = blockIdx.x * blockDim.x + threadIdx.x;
    if (i >= Nn) return;
    deg[i] = rsqrtf(deg[i] + 1.0f);
}

__global__ void gcnt_kernel(const int* __restrict__ batch, int* __restrict__ gcnt, int Nn)
{
    int i = blockIdx.x * blockDim.x + threadIdx.x;
    if (i >= Nn) return;
    atomicAdd(&gcnt[batch[i]], 1);
}

#define SCAN_BS 1024
__global__ __launch_bounds__(1024) void scan_block_kernel(
    const int* __restrict__ cnt, int* __restrict__ rowptr, int* __restrict__ bsum, int Nn)
{
    __shared__ int tmp[SCAN_BS];
    const int tid = threadIdx.x;
    const int idx = blockIdx.x * SCAN_BS + tid;
    const int v = (idx < Nn) ? cnt[idx] : 0;
    tmp[tid] = v;
    __syncthreads();
    for (int off = 1; off < SCAN_BS; off <<= 1) {
        int y = (tid >= off) ? tmp[tid - off] : 0;
        __syncthreads();
        if (tid >= off) tmp[tid] += y;
        __syncthreads();
    }
    if (idx < Nn) rowptr[idx] = tmp[tid] - v;
    if (tid == SCAN_BS - 1) bsum[blockIdx.x] = tmp[tid];
}

__global__ void scan_sums_kernel(const int* __restrict__ bsum, int* __restrict__ boff,
                                 int nb, int* __restrict__ rowptr, int Nn, int total)
{
    const int tid = threadIdx.x;
    const int orig = (tid < nb) ? bsum[tid] : 0;
    int v = orig;
    for (int off = 1; off < 64; off <<= 1) {
        int y = __shfl_up(v, off);
        if (tid >= off) v += y;
    }
    if (tid < nb) boff[tid] = v - orig;
    if (tid == 0) rowptr[Nn] = total;
}

__global__ __launch_bounds__(1024) void scan_add_kernel(
    int* __restrict__ rowptr, const int* __restrict__ boff, int Nn)
{
    const int idx = blockIdx.x * SCAN_BS + threadIdx.x;
    if (idx < Nn) rowptr[idx] += boff[blockIdx.x];
}

__global__ void fill_csr_kernel(const int* __restrict__ src, const int* __restrict__ dst,
                                const float* __restrict__ ew, const float* __restrict__ dinv,
                                const int* __restrict__ rowptr, int* __restrict__ cur,
                                int* __restrict__ csr_src, float* __restrict__ csr_norm, int E)
{
    int e = blockIdx.x * blockDim.x + threadIdx.x;
    if (e >= E) return;
    int s = src[e];
    int d = dst[e];
    float nrm = dinv[s] * ew[e] * dinv[d];
    int p = rowptr[d] + atomicAdd(&cur[d], 1);
    csr_src[p] = s;
    csr_norm[p] = nrm;
}

// ---------------------------------------------------------------------------
// conversion kernels
// ---------------------------------------------------------------------------
__global__ __launch_bounds__(256) void convert_x_kernel(
    const float* __restrict__ x, u16* __restrict__ xb, size_t total4)
{
    size_t i = (size_t)blockIdx.x * blockDim.x + threadIdx.x;
    if (i >= total4) return;
    const float4 v = *(const float4*)(x + i * 4);
    ushort4 o;
    o.x = f2bf(v.x); o.y = f2bf(v.y); o.z = f2bf(v.z); o.w = f2bf(v.w);
    *(ushort4*)(xb + i * 4) = o;
}

__global__ __launch_bounds__(256) void wtrans_kernel(
    const float* __restrict__ W, u16* __restrict__ Wt, int K, int N)
{
    __shared__ float t[32][33];
    const int tx = threadIdx.x & 31;
    const int ty = threadIdx.x >> 5;
    const int nb = blockIdx.x * 32, kb = blockIdx.y * 32;
#pragma unroll
    for (int i = 0; i < 32; i += 8)
        t[ty + i][tx] = W[(size_t)(kb + ty + i) * N + nb + tx];
    __syncthreads();
#pragma unroll
    for (int i = 0; i < 32; i += 8)
        Wt[(size_t)(nb + ty + i) * K + kb + tx] = f2bf(t[tx][ty + i]);
}

// Ut[o][k] = bf16( sum_j W2[k][j]*Wl[j][o] ), rows 8..15 zero.
// bb[o] = bl[o] + sum_j b2[j]*Wl[j][o].  grid 16 x 256 threads.
__global__ __launch_bounds__(256) void ukernel(
    const float* __restrict__ W2, const float* __restrict__ Wl,
    const float* __restrict__ b2, const float* __restrict__ bl,
    u16* __restrict__ Ut, float* __restrict__ bb, int H)
{
    const int t = threadIdx.x;
    const int k = blockIdx.x * 32 + (t >> 3);
    const int o = t & 7;
    float acc = 0.f;
    for (int j = 0; j < H; ++j)
        acc = fmaf(W2[(size_t)k * 8 * (H / 8) + j], Wl[j * 8 + o], acc);  // W2[k][j], row len H
    Ut[(size_t)o * H + k] = f2bf(acc);
    Ut[(size_t)(o + 8) * H + k] = 0;
    if (blockIdx.x == 0 && t < 8) {
        float s = bl[t];
        for (int j = 0; j < H; ++j)
            s = fmaf(b2[j], Wl[j * 8 + t], s);
        bb[t] = s;
    }
}

// ---------------------------------------------------------------------------
// aggregation layer 1: out[n] = relu(bias + dinv^2*hw[n] + sum norm*hw[src])
// ---------------------------------------------------------------------------
template <int RELU>
__global__ __launch_bounds__(128) void agg_kernel(
    const u16* __restrict__ hw, const float* __restrict__ dinv,
    const int* __restrict__ rowptr, const int* __restrict__ csr_src,
    const float* __restrict__ csr_norm, const float* __restrict__ bias,
    u16* __restrict__ outp)
{
    const int n = blockIdx.x;
    const int c = threadIdx.x * 4;
    const float di = dinv[n];
    float4 acc = *(const float4*)(bias + c);
    {
        const float s = di * di;
        const ushort4 hv = *(const ushort4*)(hw + (size_t)n * 512 + c);
        acc.x = fmaf(s, bf2f(hv.x), acc.x);
        acc.y = fmaf(s, bf2f(hv.y), acc.y);
        acc.z = fmaf(s, bf2f(hv.z), acc.z);
        acc.w = fmaf(s, bf2f(hv.w), acc.w);
    }
    const int beg = rowptr[n];
    const int end = rowptr[n + 1];
    for (int i = beg; i < end; ++i) {
        const int s = csr_src[i];
        const float nr = csr_norm[i];
        const ushort4 v = *(const ushort4*)(hw + (size_t)s * 512 + c);
        acc.x = fmaf(nr, bf2f(v.x), acc.x);
        acc.y = fmaf(nr, bf2f(v.y), acc.y);
        acc.z = fmaf(nr, bf2f(v.z), acc.z);
        acc.w = fmaf(nr, bf2f(v.w), acc.w);
    }
    if (RELU) {
        acc.x = fmaxf(acc.x, 0.f);
        acc.y = fmaxf(acc.y, 0.f);
        acc.z = fmaxf(acc.z, 0.f);
        acc.w = fmaxf(acc.w, 0.f);
    }
    ushort4 o;
    o.x = f2bf(acc.x); o.y = f2bf(acc.y); o.z = f2bf(acc.z); o.w = f2bf(acc.w);
    *(ushort4*)(outp + (size_t)n * 512 + c) = o;
}

// ---------------------------------------------------------------------------
// mini-agg on 8 cols: z[n][o] = dinv^2*Y[n][o] + sum norm*Y[src][o];
// atomically pooled into gsum[batch[n]][o]. block 256 = 32 nodes x 8 cols.
// ---------------------------------------------------------------------------
__global__ __launch_bounds__(256) void mini_agg_kernel(
    const float* __restrict__ Y, const float* __restrict__ dinv,
    const int* __restrict__ rowptr, const int* __restrict__ csr_src,
    const float* __restrict__ csr_norm, const int* __restrict__ batch,
    float* __restrict__ gsum, int Nn)
{
    const int t = threadIdx.x;
    const int n = blockIdx.x * 32 + (t >> 3);
    const int o = t & 7;
    if (n >= Nn) return;
    const float di = dinv[n];
    float acc = di * di * Y[(size_t)n * 8 + o];
    const int beg = rowptr[n];
    const int end = rowptr[n + 1];
    for (int i = beg; i < end; ++i)
        acc = fmaf(csr_norm[i], Y[(size_t)csr_src[i] * 8 + o], acc);
    atomicAdd(&gsum[(size_t)batch[n] * 8 + o], acc);
}

__global__ void final8_kernel(const float* __restrict__ gsum, const int* __restrict__ gcnt,
                              const float* __restrict__ bb, float* __restrict__ out)
{
    const int t = threadIdx.x;  // 512 threads: g = t>>3, o = t&7
    const int g = t >> 3, o = t & 7;
    const int c = gcnt[g];
    out[g * 8 + o] = gsum[g * 8 + o] / (float)(c > 0 ? c : 1) + bb[o];
}

// ---------------------------------------------------------------------------
extern "C" void kernel_launch(void* const* d_in, const int* in_sizes, int n_in,
                              void* d_out, int out_size, void* d_ws, size_t ws_size,
                              hipStream_t stream)
{
    const float* x    = (const float*)d_in[0];
    const int*   eidx = (const int*)d_in[1];
    const int*   batch= (const int*)d_in[2];
    const float* ew   = (const float*)d_in[3];
    const float* W1   = (const float*)d_in[4];
    const float* b1   = (const float*)d_in[5];
    const float* W2   = (const float*)d_in[6];
    const float* b2   = (const float*)d_in[7];
    const float* Wl   = (const float*)d_in[8];
    const float* bl   = (const float*)d_in[9];
    float* out = (float*)d_out;

    const int Nn = in_sizes[2];            // 50000
    const int Ee = in_sizes[3];            // 800000
    const int F  = in_sizes[0] / Nn;       // 512
    const int H  = in_sizes[5];            // 512
    const int Mpad = (Nn + BM - 1) / BM * BM;

    const int* src = eidx;
    const int* dst = eidx + Ee;

    char* base = (char*)d_ws;
    size_t off = 0;
    auto alloc = [&](size_t bytes) -> char* {
        char* p = base + off;
        off += (bytes + 255) & ~(size_t)255;
        return p;
    };
    u16* xb  = (u16*)alloc((size_t)Mpad * F * sizeof(u16));
    u16* hb0 = (u16*)alloc((size_t)Mpad * H * sizeof(u16));   // T1 = x@W1
    u16* hb1 = (u16*)alloc((size_t)Mpad * H * sizeof(u16));   // H1
    u16* Wt1 = (u16*)alloc((size_t)F * H * sizeof(u16));
    u16* Ut  = (u16*)alloc((size_t)16 * H * sizeof(u16));
    float* Yb = (float*)alloc((size_t)Mpad * 8 * sizeof(float));
    float* bb = (float*)alloc(8 * sizeof(float));
    char* zero_begin = base + off;
    float* deg  = (float*)alloc((size_t)Nn * sizeof(float));  // becomes dinv
    int*   cnt  = (int*)alloc((size_t)Nn * sizeof(int));
    int*   cur  = (int*)alloc((size_t)Nn * sizeof(int));
    float* gsum = (float*)alloc((size_t)64 * 8 * sizeof(float));
    int*   gcnt = (int*)alloc((size_t)64 * sizeof(int));
    char* zero_end = base + off;
    int*   rowptr   = (int*)alloc((size_t)(Nn + 1) * sizeof(int));
    int*   bsum     = (int*)alloc(64 * sizeof(int));
    int*   boff     = (int*)alloc(64 * sizeof(int));
    int*   csr_src  = (int*)alloc((size_t)Ee * sizeof(int));
    float* csr_norm = (float*)alloc((size_t)Ee * sizeof(float));
    (void)ws_size;

    hipMemsetAsync(zero_begin, 0, (size_t)(zero_end - zero_begin), stream);

    const int nb = (Nn + SCAN_BS - 1) / SCAN_BS;
    deg_cnt_kernel<<<(Ee + 255) / 256, 256, 0, stream>>>(dst, ew, deg, cnt, Ee);
    gcnt_kernel<<<(Nn + 255) / 256, 256, 0, stream>>>(batch, gcnt, Nn);
    dinv_kernel<<<(Nn + 255) / 256, 256, 0, stream>>>(deg, Nn);
    scan_block_kernel<<<nb, SCAN_BS, 0, stream>>>(cnt, rowptr, bsum, Nn);
    scan_sums_kernel<<<1, 64, 0, stream>>>(bsum, boff, nb, rowptr, Nn, Ee);
    scan_add_kernel<<<nb, SCAN_BS, 0, stream>>>(rowptr, boff, Nn);
    fill_csr_kernel<<<(Ee + 255) / 256, 256, 0, stream>>>(src, dst, ew, deg, rowptr, cur,
                                                          csr_src, csr_norm, Ee);

    const size_t total4 = (size_t)Nn * F / 4;
    convert_x_kernel<<<(int)((total4 + 255) / 256), 256, 0, stream>>>(x, xb, total4);
    wtrans_kernel<<<dim3(H / 32, F / 32), 256, 0, stream>>>(W1, Wt1, F, H);
    ukernel<<<16, 256, 0, stream>>>(W2, Wl, b2, bl, Ut, bb, H);

    dim3 ggrid(H / BN, Mpad / BM);
    // layer 1
    gemm_bf16_kernel<<<ggrid, 256, 0, stream>>>(xb, Wt1, hb0, Nn, H, F);
    agg_kernel<1><<<Nn, 128, 0, stream>>>(hb0, deg, rowptr, csr_src, csr_norm, b1, hb1);
    // collapsed layer 2 + pool + linear
    gemmY_kernel<<<Mpad / 128, 256, 0, stream>>>(hb1, Ut, Yb, H);
    mini_agg_kernel<<<(Nn + 31) / 32, 256, 0, stream>>>(Yb, deg, rowptr, csr_src, csr_norm,
                                                        batch, gsum, Nn);
    final8_kernel<<<1, 512, 0, stream>>>(gsum, gcnt, bb, out);
}

// Round 4
// 490.717 us; speedup vs baseline: 1.5891x; 1.5891x over previous
//
#include <hip/hip_runtime.h>
#include <cstddef>
#include <cstdint>

// ---------------------------------------------------------------------------
// GCN pipeline, restructured + atomic-free pooling:
//   out = P @ A_hat @ (H1 @ U) + bb,   U = W2@Wl [512x8], bb = b2@Wl + bl
// Stages:
//   deg/dinv -> CSR -> gstart (sorted-batch boundaries) -> convert x/W1 ->
//   GEMM1(bf16 MFMA) -> AGG1(+relu) -> Y=H1@U (MFMA) -> Z=A_hat@Y (8 cols) ->
//   per-graph pool (no atomics) -> out
// Rule learned R3: same-address cross-XCD atomics ~300ns each; avoid funnels.
// ---------------------------------------------------------------------------

typedef unsigned short u16;
typedef short s16x8 __attribute__((ext_vector_type(8)));
typedef float f32x4 __attribute__((ext_vector_type(4)));

__device__ __forceinline__ float bf2f(u16 h) {
    union { unsigned int u; float f; } c; c.u = ((unsigned int)h) << 16; return c.f;
}
__device__ __forceinline__ u16 f2bf(float f) {
    union { float f; unsigned int u; } c; c.f = f;
    unsigned int u = c.u;
    u += 0x7FFFu + ((u >> 16) & 1u);   // round-to-nearest-even
    return (u16)(u >> 16);
}

#define GLD_LDS16(g, l) __builtin_amdgcn_global_load_lds( \
    (const __attribute__((address_space(1))) unsigned int*)(const void*)(g), \
    (__attribute__((address_space(3))) unsigned int*)(void*)(l), 16, 0, 0)

#define BM 128
#define BN 128
#define BKK 32

// ---------------------------------------------------------------------------
// bf16 MFMA GEMM: C[M,N]=A[M,K]@B[K,N]; Bt=B^T [N][K] bf16; C bf16.
// ---------------------------------------------------------------------------
__global__ __launch_bounds__(256) void gemm_bf16_kernel(
    const u16* __restrict__ A, const u16* __restrict__ Bt,
    u16* __restrict__ C, int M, int N, int K)
{
    __shared__ u16 As[BM * BKK];
    __shared__ u16 Bs[BN * BKK];
    const int tid = threadIdx.x;
    const int lane = tid & 63;
    const int wave = tid >> 6;
    const int wr = wave >> 1, wc = wave & 1;
    const int m0 = blockIdx.y * BM;
    const int n0 = blockIdx.x * BN;

    const int srow = tid >> 2;
    const int scol = (tid & 3) * 8;

    f32x4 acc[4][4] = {};

    const u16* aptr0 = A + (size_t)(m0 + srow) * K + scol;
    const u16* aptr1 = A + (size_t)(m0 + srow + 64) * K + scol;
    const u16* bptr0 = Bt + (size_t)(n0 + srow) * K + scol;
    const u16* bptr1 = Bt + (size_t)(n0 + srow + 64) * K + scol;

    for (int k0 = 0; k0 < K; k0 += BKK) {
        GLD_LDS16(aptr0 + k0, As + (size_t)tid * 8);
        GLD_LDS16(aptr1 + k0, As + (size_t)(256 + tid) * 8);
        GLD_LDS16(bptr0 + k0, Bs + (size_t)tid * 8);
        GLD_LDS16(bptr1 + k0, Bs + (size_t)(256 + tid) * 8);
        __syncthreads();

        s16x8 af[4], bfr[4];
#pragma unroll
        for (int mi = 0; mi < 4; ++mi)
            af[mi] = *(const s16x8*)(As + (wr * 64 + mi * 16 + (lane & 15)) * BKK + (lane >> 4) * 8);
#pragma unroll
        for (int nj = 0; nj < 4; ++nj)
            bfr[nj] = *(const s16x8*)(Bs + (wc * 64 + nj * 16 + (lane & 15)) * BKK + (lane >> 4) * 8);
#pragma unroll
        for (int mi = 0; mi < 4; ++mi)
#pragma unroll
            for (int nj = 0; nj < 4; ++nj)
                acc[mi][nj] = __builtin_amdgcn_mfma_f32_16x16x32_bf16(af[mi], bfr[nj], acc[mi][nj], 0, 0, 0);
        __syncthreads();
    }

    const int crow = (lane >> 4) * 4;
    const int ccol = lane & 15;
#pragma unroll
    for (int mi = 0; mi < 4; ++mi) {
        const int gr0 = m0 + wr * 64 + mi * 16 + crow;
#pragma unroll
        for (int r = 0; r < 4; ++r) {
            const int gr = gr0 + r;
            if (gr < M) {
#pragma unroll
                for (int nj = 0; nj < 4; ++nj)
                    C[(size_t)gr * N + n0 + wc * 64 + nj * 16 + ccol] = f2bf(acc[mi][nj][r]);
            }
        }
    }
}

// ---------------------------------------------------------------------------
// Y[M,8] = A[M,512] @ U[512,8] (fp32 out); Ut = U^T padded to [16][512] bf16.
// ---------------------------------------------------------------------------
__global__ __launch_bounds__(256) void gemmY_kernel(
    const u16* __restrict__ A, const u16* __restrict__ Ut,
    float* __restrict__ Y, int K)
{
    __shared__ u16 As[128 * 32];
    const int tid = threadIdx.x;
    const int lane = tid & 63;
    const int wave = tid >> 6;
    const int m0 = blockIdx.x * 128;
    const int srow = tid >> 2;
    const int scol = (tid & 3) * 8;

    f32x4 acc[2] = {};
    const u16* a0 = A + (size_t)(m0 + srow) * K + scol;
    const u16* a1 = A + (size_t)(m0 + 64 + srow) * K + scol;

    for (int k0 = 0; k0 < K; k0 += 32) {
        GLD_LDS16(a0 + k0, As + (size_t)tid * 8);
        GLD_LDS16(a1 + k0, As + (size_t)(256 + tid) * 8);
        s16x8 bfr = *(const s16x8*)(Ut + (size_t)(lane & 15) * K + k0 + (lane >> 4) * 8);
        __syncthreads();
        s16x8 af0 = *(const s16x8*)(As + (wave * 32 + (lane & 15)) * 32 + (lane >> 4) * 8);
        s16x8 af1 = *(const s16x8*)(As + (wave * 32 + 16 + (lane & 15)) * 32 + (lane >> 4) * 8);
        acc[0] = __builtin_amdgcn_mfma_f32_16x16x32_bf16(af0, bfr, acc[0], 0, 0, 0);
        acc[1] = __builtin_amdgcn_mfma_f32_16x16x32_bf16(af1, bfr, acc[1], 0, 0, 0);
        __syncthreads();
    }
    const int ccol = lane & 15;
    if (ccol < 8) {
        const int crow = (lane >> 4) * 4;
#pragma unroll
        for (int mi = 0; mi < 2; ++mi)
#pragma unroll
            for (int r = 0; r < 4; ++r)
                Y[(size_t)(m0 + wave * 32 + mi * 16 + crow + r) * 8 + ccol] = acc[mi][r];
    }
}

// ---------------------------------------------------------------------------
// setup kernels
// ---------------------------------------------------------------------------
__global__ void deg_cnt_kernel(const int* __restrict__ dst, const float* __restrict__ ew,
                               float* __restrict__ deg, int* __restrict__ cnt, int E)
{
    int e = blockIdx.x * blockDim.x + threadIdx.x;
    if (e >= E) return;
    int d = dst[e];
    atomicAdd(&deg[d], ew[e]);
    atomicAdd(&cnt[d], 1);
}

__global__ void dinv_kernel(float* __restrict__ deg, int Nn)
{
    int i = blockIdx.x * blockDim.x + threadIdx.x;
    if (i >= Nn) return;
    deg[i] = rsqrtf(deg[i] + 1.0f);
}

// sorted-batch boundary detection: gstart[g] = first node index of graph g;
// gstart[G] = Nn. Handles empty graphs. Zero atomics.
__global__ void gstart_kernel(const int* __restrict__ batch, int* __restrict__ gstart,
                              int Nn, int G)
{
    int i = blockIdx.x * blockDim.x + threadIdx.x;
    if (i >= Nn) return;
    int b = batch[i];
    int prev = (i == 0) ? -1 : batch[i - 1];
    for (int g = prev + 1; g <= b; ++g) gstart[g] = i;
    if (i == Nn - 1)
        for (int g = b + 1; g <= G; ++g) gstart[g] = Nn;
}

#define SCAN_BS 1024
__global__ __launch_bounds__(1024) void scan_block_kernel(
    const int* __restrict__ cnt, int* __restrict__ rowptr, int* __restrict__ bsum, int Nn)
{
    __shared__ int tmp[SCAN_BS];
    const int tid = threadIdx.x;
    const int idx = blockIdx.x * SCAN_BS + tid;
    const int v = (idx < Nn) ? cnt[idx] : 0;
    tmp[tid] = v;
    __syncthreads();
    for (int off = 1; off < SCAN_BS; off <<= 1) {
        int y = (tid >= off) ? tmp[tid - off] : 0;
        __syncthreads();
        if (tid >= off) tmp[tid] += y;
        __syncthreads();
    }
    if (idx < Nn) rowptr[idx] = tmp[tid] - v;
    if (tid == SCAN_BS - 1) bsum[blockIdx.x] = tmp[tid];
}

__global__ void scan_sums_kernel(const int* __restrict__ bsum, int* __restrict__ boff,
                                 int nb, int* __restrict__ rowptr, int Nn, int total)
{
    const int tid = threadIdx.x;
    const int orig = (tid < nb) ? bsum[tid] : 0;
    int v = orig;
    for (int off = 1; off < 64; off <<= 1) {
        int y = __shfl_up(v, off);
        if (tid >= off) v += y;
    }
    if (tid < nb) boff[tid] = v - orig;
    if (tid == 0) rowptr[Nn] = total;
}

__global__ __launch_bounds__(1024) void scan_add_kernel(
    int* __restrict__ rowptr, const int* __restrict__ boff, int Nn)
{
    const int idx = blockIdx.x * SCAN_BS + threadIdx.x;
    if (idx < Nn) rowptr[idx] += boff[blockIdx.x];
}

__global__ void fill_csr_kernel(const int* __restrict__ src, const int* __restrict__ dst,
                                const float* __restrict__ ew, const float* __restrict__ dinv,
                                const int* __restrict__ rowptr, int* __restrict__ cur,
                                int* __restrict__ csr_src, float* __restrict__ csr_norm, int E)
{
    int e = blockIdx.x * blockDim.x + threadIdx.x;
    if (e >= E) return;
    int s = src[e];
    int d = dst[e];
    float nrm = dinv[s] * ew[e] * dinv[d];
    int p = rowptr[d] + atomicAdd(&cur[d], 1);
    csr_src[p] = s;
    csr_norm[p] = nrm;
}

// ---------------------------------------------------------------------------
// conversion kernels
// ---------------------------------------------------------------------------
__global__ __launch_bounds__(256) void convert_x_kernel(
    const float* __restrict__ x, u16* __restrict__ xb, size_t total4)
{
    size_t i = (size_t)blockIdx.x * blockDim.x + threadIdx.x;
    if (i >= total4) return;
    const float4 v = *(const float4*)(x + i * 4);
    ushort4 o;
    o.x = f2bf(v.x); o.y = f2bf(v.y); o.z = f2bf(v.z); o.w = f2bf(v.w);
    *(ushort4*)(xb + i * 4) = o;
}

__global__ __launch_bounds__(256) void wtrans_kernel(
    const float* __restrict__ W, u16* __restrict__ Wt, int K, int N)
{
    __shared__ float t[32][33];
    const int tx = threadIdx.x & 31;
    const int ty = threadIdx.x >> 5;
    const int nb = blockIdx.x * 32, kb = blockIdx.y * 32;
#pragma unroll
    for (int i = 0; i < 32; i += 8)
        t[ty + i][tx] = W[(size_t)(kb + ty + i) * N + nb + tx];
    __syncthreads();
#pragma unroll
    for (int i = 0; i < 32; i += 8)
        Wt[(size_t)(nb + ty + i) * K + kb + tx] = f2bf(t[tx][ty + i]);
}

// Ut[o][k] = bf16( sum_j W2[k][j]*Wl[j][o] ), rows 8..15 zero.
// bb[o] = bl[o] + sum_j b2[j]*Wl[j][o].
__global__ __launch_bounds__(256) void ukernel(
    const float* __restrict__ W2, const float* __restrict__ Wl,
    const float* __restrict__ b2, const float* __restrict__ bl,
    u16* __restrict__ Ut, float* __restrict__ bb, int H)
{
    const int t = threadIdx.x;
    const int k = blockIdx.x * 32 + (t >> 3);
    const int o = t & 7;
    float acc = 0.f;
    for (int j = 0; j < H; ++j)
        acc = fmaf(W2[(size_t)k * H + j], Wl[j * 8 + o], acc);
    Ut[(size_t)o * H + k] = f2bf(acc);
    Ut[(size_t)(o + 8) * H + k] = 0;
    if (blockIdx.x == 0 && t < 8) {
        float s = bl[t];
        for (int j = 0; j < H; ++j)
            s = fmaf(b2[j], Wl[j * 8 + t], s);
        bb[t] = s;
    }
}

// ---------------------------------------------------------------------------
// aggregation layer 1: out[n] = relu(bias + dinv^2*hw[n] + sum norm*hw[src])
// ---------------------------------------------------------------------------
template <int RELU>
__global__ __launch_bounds__(128) void agg_kernel(
    const u16* __restrict__ hw, const float* __restrict__ dinv,
    const int* __restrict__ rowptr, const int* __restrict__ csr_src,
    const float* __restrict__ csr_norm, const float* __restrict__ bias,
    u16* __restrict__ outp)
{
    const int n = blockIdx.x;
    const int c = threadIdx.x * 4;
    const float di = dinv[n];
    float4 acc = *(const float4*)(bias + c);
    {
        const float s = di * di;
        const ushort4 hv = *(const ushort4*)(hw + (size_t)n * 512 + c);
        acc.x = fmaf(s, bf2f(hv.x), acc.x);
        acc.y = fmaf(s, bf2f(hv.y), acc.y);
        acc.z = fmaf(s, bf2f(hv.z), acc.z);
        acc.w = fmaf(s, bf2f(hv.w), acc.w);
    }
    const int beg = rowptr[n];
    const int end = rowptr[n + 1];
    for (int i = beg; i < end; ++i) {
        const int s = csr_src[i];
        const float nr = csr_norm[i];
        const ushort4 v = *(const ushort4*)(hw + (size_t)s * 512 + c);
        acc.x = fmaf(nr, bf2f(v.x), acc.x);
        acc.y = fmaf(nr, bf2f(v.y), acc.y);
        acc.z = fmaf(nr, bf2f(v.z), acc.z);
        acc.w = fmaf(nr, bf2f(v.w), acc.w);
    }
    if (RELU) {
        acc.x = fmaxf(acc.x, 0.f);
        acc.y = fmaxf(acc.y, 0.f);
        acc.z = fmaxf(acc.z, 0.f);
        acc.w = fmaxf(acc.w, 0.f);
    }
    ushort4 o;
    o.x = f2bf(acc.x); o.y = f2bf(acc.y); o.z = f2bf(acc.z); o.w = f2bf(acc.w);
    *(ushort4*)(outp + (size_t)n * 512 + c) = o;
}

// ---------------------------------------------------------------------------
// mini-agg on 8 cols: Z[n][o] = dinv^2*Y[n][o] + sum norm*Y[src][o]
// (no pooling here — atomic-free). block 256 = 32 nodes x 8 cols.
// ---------------------------------------------------------------------------
__global__ __launch_bounds__(256) void mini_agg_kernel(
    const float* __restrict__ Y, const float* __restrict__ dinv,
    const int* __restrict__ rowptr, const int* __restrict__ csr_src,
    const float* __restrict__ csr_norm, float* __restrict__ Z, int Nn)
{
    const int t = threadIdx.x;
    const int n = blockIdx.x * 32 + (t >> 3);
    const int o = t & 7;
    if (n >= Nn) return;
    const float di = dinv[n];
    float acc = di * di * Y[(size_t)n * 8 + o];
    const int beg = rowptr[n];
    const int end = rowptr[n + 1];
    for (int i = beg; i < end; ++i)
        acc = fmaf(csr_norm[i], Y[(size_t)csr_src[i] * 8 + o], acc);
    Z[(size_t)n * 8 + o] = acc;
}

// ---------------------------------------------------------------------------
// per-graph mean pool + bias: one block per graph, no atomics.
// out[g][o] = mean_{n in [gstart[g],gstart[g+1])} Z[n][o] + bb[o]
// ---------------------------------------------------------------------------
__global__ __launch_bounds__(256) void pool8_kernel(
    const float* __restrict__ Z, const int* __restrict__ gstart,
    const float* __restrict__ bb, float* __restrict__ out)
{
    const int g = blockIdx.x;
    const int t = threadIdx.x;
    const int grp = t >> 3;          // 0..31
    const int o = t & 7;
    const int beg = gstart[g], end = gstart[g + 1];
    float acc = 0.f;
    for (int n = beg + grp; n < end; n += 32)
        acc += Z[(size_t)n * 8 + o];
    // reduce the 8 groups within each wave (lanes grp_local*8+o)
    acc += __shfl_xor(acc, 8);
    acc += __shfl_xor(acc, 16);
    acc += __shfl_xor(acc, 32);
    __shared__ float red[4][8];
    const int lane = t & 63;
    const int wid = t >> 6;
    if (lane < 8) red[wid][lane] = acc;
    __syncthreads();
    if (t < 8) {
        const int c = end - beg;
        const float inv = 1.0f / (float)(c > 0 ? c : 1);
        out[g * 8 + t] = (red[0][t] + red[1][t] + red[2][t] + red[3][t]) * inv + bb[t];
    }
}

// ---------------------------------------------------------------------------
extern "C" void kernel_launch(void* const* d_in, const int* in_sizes, int n_in,
                              void* d_out, int out_size, void* d_ws, size_t ws_size,
                              hipStream_t stream)
{
    const float* x    = (const float*)d_in[0];
    const int*   eidx = (const int*)d_in[1];
    const int*   batch= (const int*)d_in[2];
    const float* ew   = (const float*)d_in[3];
    const float* W1   = (const float*)d_in[4];
    const float* b1   = (const float*)d_in[5];
    const float* W2   = (const float*)d_in[6];
    const float* b2   = (const float*)d_in[7];
    const float* Wl   = (const float*)d_in[8];
    const float* bl   = (const float*)d_in[9];
    float* out = (float*)d_out;

    const int Nn = in_sizes[2];            // 50000
    const int Ee = in_sizes[3];            // 800000
    const int F  = in_sizes[0] / Nn;       // 512
    const int H  = in_sizes[5];            // 512
    const int G  = 64;
    const int Mpad = (Nn + BM - 1) / BM * BM;

    const int* src = eidx;
    const int* dst = eidx + Ee;

    char* base = (char*)d_ws;
    size_t off = 0;
    auto alloc = [&](size_t bytes) -> char* {
        char* p = base + off;
        off += (bytes + 255) & ~(size_t)255;
        return p;
    };
    u16* xb  = (u16*)alloc((size_t)Mpad * F * sizeof(u16));
    u16* hb0 = (u16*)alloc((size_t)Mpad * H * sizeof(u16));   // T1 = x@W1
    u16* hb1 = (u16*)alloc((size_t)Mpad * H * sizeof(u16));   // H1
    u16* Wt1 = (u16*)alloc((size_t)F * H * sizeof(u16));
    u16* Ut  = (u16*)alloc((size_t)16 * H * sizeof(u16));
    float* Yb = (float*)alloc((size_t)Mpad * 8 * sizeof(float));
    float* Zb = (float*)alloc((size_t)Mpad * 8 * sizeof(float));
    float* bb = (float*)alloc(8 * sizeof(float));
    char* zero_begin = base + off;
    float* deg  = (float*)alloc((size_t)Nn * sizeof(float));  // becomes dinv
    int*   cnt  = (int*)alloc((size_t)Nn * sizeof(int));
    int*   cur  = (int*)alloc((size_t)Nn * sizeof(int));
    char* zero_end = base + off;
    int*   gstart   = (int*)alloc((size_t)(G + 1) * sizeof(int));
    int*   rowptr   = (int*)alloc((size_t)(Nn + 1) * sizeof(int));
    int*   bsum     = (int*)alloc(64 * sizeof(int));
    int*   boff     = (int*)alloc(64 * sizeof(int));
    int*   csr_src  = (int*)alloc((size_t)Ee * sizeof(int));
    float* csr_norm = (float*)alloc((size_t)Ee * sizeof(float));
    (void)ws_size;

    hipMemsetAsync(zero_begin, 0, (size_t)(zero_end - zero_begin), stream);

    const int nb = (Nn + SCAN_BS - 1) / SCAN_BS;
    deg_cnt_kernel<<<(Ee + 255) / 256, 256, 0, stream>>>(dst, ew, deg, cnt, Ee);
    gstart_kernel<<<(Nn + 255) / 256, 256, 0, stream>>>(batch, gstart, Nn, G);
    dinv_kernel<<<(Nn + 255) / 256, 256, 0, stream>>>(deg, Nn);
    scan_block_kernel<<<nb, SCAN_BS, 0, stream>>>(cnt, rowptr, bsum, Nn);
    scan_sums_kernel<<<1, 64, 0, stream>>>(bsum, boff, nb, rowptr, Nn, Ee);
    scan_add_kernel<<<nb, SCAN_BS, 0, stream>>>(rowptr, boff, Nn);
    fill_csr_kernel<<<(Ee + 255) / 256, 256, 0, stream>>>(src, dst, ew, deg, rowptr, cur,
                                                          csr_src, csr_norm, Ee);

    const size_t total4 = (size_t)Nn * F / 4;
    convert_x_kernel<<<(int)((total4 + 255) / 256), 256, 0, stream>>>(x, xb, total4);
    wtrans_kernel<<<dim3(H / 32, F / 32), 256, 0, stream>>>(W1, Wt1, F, H);
    ukernel<<<16, 256, 0, stream>>>(W2, Wl, b2, bl, Ut, bb, H);

    dim3 ggrid(H / BN, Mpad / BM);
    // layer 1
    gemm_bf16_kernel<<<ggrid, 256, 0, stream>>>(xb, Wt1, hb0, Nn, H, F);
    agg_kernel<1><<<Nn, 128, 0, stream>>>(hb0, deg, rowptr, csr_src, csr_norm, b1, hb1);
    // collapsed layer 2 + pool + linear
    gemmY_kernel<<<Mpad / 128, 256, 0, stream>>>(hb1, Ut, Yb, H);
    mini_agg_kernel<<<(Nn + 31) / 32, 256, 0, stream>>>(Yb, deg, rowptr, csr_src, csr_norm,
                                                        Zb, Nn);
    pool8_kernel<<<G, 256, 0, stream>>>(Zb, gstart, bb, out);
}

// Round 5
// 482.887 us; speedup vs baseline: 1.6149x; 1.0162x over previous
//
#include <hip/hip_runtime.h>
#include <cstddef>
#include <cstdint>

// ---------------------------------------------------------------------------
// GCN pipeline, fully fused:
//   out = P @ A_hat @ (relu(A_hat@(X@W1)+b1) @ U) + bb,  U=W2@Wl, bb=b2@Wl+bl
// Dispatches (9):
//   memset -> K1{deg_cnt|gstart|convert_x|wtrans(W1)|ukernel} ->
//   K2{dinv|scan_block} -> K3{scan_sums} -> K4{fill_csr|rowptr_final} ->
//   GEMM1(bf16 MFMA, BN=256) -> AGG1+relu+proj8 (fused) -> mini_agg -> pool8
// Rules learned: R3 same-address cross-XCD atomics ~300ns each — avoid funnels.
// R4: prep-chain dispatch count is ~half the runtime — fuse independent work.
// ---------------------------------------------------------------------------

typedef unsigned short u16;
typedef short s16x8 __attribute__((ext_vector_type(8)));
typedef float f32x4 __attribute__((ext_vector_type(4)));

__device__ __forceinline__ float bf2f(u16 h) {
    union { unsigned int u; float f; } c; c.u = ((unsigned int)h) << 16; return c.f;
}
__device__ __forceinline__ u16 f2bf(float f) {
    union { float f; unsigned int u; } c; c.f = f;
    unsigned int u = c.u;
    u += 0x7FFFu + ((u >> 16) & 1u);   // round-to-nearest-even
    return (u16)(u >> 16);
}

#define GLD_LDS16(g, l) __builtin_amdgcn_global_load_lds( \
    (const __attribute__((address_space(1))) unsigned int*)(const void*)(g), \
    (__attribute__((address_space(3))) unsigned int*)(void*)(l), 16, 0, 0)

#define BM 128
#define BN 256
#define BKK 32

// ---------------------------------------------------------------------------
// bf16 MFMA GEMM: C[M,N]=A[M,K]@B[K,N]; Bt=B^T [N][K] bf16; C bf16.
// 128x256 tile, 4 waves (2M x 2N), each wave 64x128 -> acc[4][8].
// ---------------------------------------------------------------------------
__global__ __launch_bounds__(256) void gemm_bf16_kernel(
    const u16* __restrict__ A, const u16* __restrict__ Bt,
    u16* __restrict__ C, int M, int N, int K)
{
    __shared__ u16 As[BM * BKK];   // 8 KB
    __shared__ u16 Bs[BN * BKK];   // 16 KB
    const int tid = threadIdx.x;
    const int lane = tid & 63;
    const int wave = tid >> 6;
    const int wr = wave >> 1, wc = wave & 1;
    const int m0 = blockIdx.y * BM;
    const int n0 = blockIdx.x * BN;

    const int srow = tid >> 2;
    const int scol = (tid & 3) * 8;

    f32x4 acc[4][8] = {};

    const u16* aptr0 = A + (size_t)(m0 + srow) * K + scol;
    const u16* aptr1 = A + (size_t)(m0 + srow + 64) * K + scol;
    const u16* bptr0 = Bt + (size_t)(n0 + srow) * K + scol;
    const u16* bptr1 = Bt + (size_t)(n0 + srow + 64) * K + scol;
    const u16* bptr2 = Bt + (size_t)(n0 + srow + 128) * K + scol;
    const u16* bptr3 = Bt + (size_t)(n0 + srow + 192) * K + scol;

    for (int k0 = 0; k0 < K; k0 += BKK) {
        GLD_LDS16(aptr0 + k0, As + (size_t)tid * 8);
        GLD_LDS16(aptr1 + k0, As + (size_t)(256 + tid) * 8);
        GLD_LDS16(bptr0 + k0, Bs + (size_t)tid * 8);
        GLD_LDS16(bptr1 + k0, Bs + (size_t)(256 + tid) * 8);
        GLD_LDS16(bptr2 + k0, Bs + (size_t)(512 + tid) * 8);
        GLD_LDS16(bptr3 + k0, Bs + (size_t)(768 + tid) * 8);
        __syncthreads();

        s16x8 af[4], bfr[8];
#pragma unroll
        for (int mi = 0; mi < 4; ++mi)
            af[mi] = *(const s16x8*)(As + (wr * 64 + mi * 16 + (lane & 15)) * BKK + (lane >> 4) * 8);
#pragma unroll
        for (int nj = 0; nj < 8; ++nj)
            bfr[nj] = *(const s16x8*)(Bs + (wc * 128 + nj * 16 + (lane & 15)) * BKK + (lane >> 4) * 8);
#pragma unroll
        for (int mi = 0; mi < 4; ++mi)
#pragma unroll
            for (int nj = 0; nj < 8; ++nj)
                acc[mi][nj] = __builtin_amdgcn_mfma_f32_16x16x32_bf16(af[mi], bfr[nj], acc[mi][nj], 0, 0, 0);
        __syncthreads();
    }

    const int crow = (lane >> 4) * 4;
    const int ccol = lane & 15;
#pragma unroll
    for (int mi = 0; mi < 4; ++mi) {
        const int gr0 = m0 + wr * 64 + mi * 16 + crow;
#pragma unroll
        for (int r = 0; r < 4; ++r) {
            const int gr = gr0 + r;
            if (gr < M) {
#pragma unroll
                for (int nj = 0; nj < 8; ++nj)
                    C[(size_t)gr * N + n0 + wc * 128 + nj * 16 + ccol] = f2bf(acc[mi][nj][r]);
            }
        }
    }
}

// ---------------------------------------------------------------------------
// K1: fused independent prep. Roles by blockIdx range (256 threads each):
//   [0,EB)            deg_cnt:  deg[dst]+=ew, cnt[dst]++        (E threads)
//   [EB,EB+NB)        gstart:   sorted-batch boundaries
//   [C0,C0+CB)        convert_x: fp32 -> bf16 (float4/ushort4)
//   [W0,W0+256)       wtrans:   Wt1[n][k] = bf16(W1[k][n])
//   [U0,U0+16)        ukernel:  Ub[k][o]=bf16(sum_j W2[k][j]Wl[j][o]); bb
// ---------------------------------------------------------------------------
__global__ __launch_bounds__(256) void prep_kernel(
    const int* __restrict__ dst, const float* __restrict__ ew,
    float* __restrict__ deg, int* __restrict__ cnt,
    const int* __restrict__ batch, int* __restrict__ gstart,
    const float* __restrict__ x, u16* __restrict__ xb,
    const float* __restrict__ W1, u16* __restrict__ Wt1,
    const float* __restrict__ W2, const float* __restrict__ Wl,
    const float* __restrict__ b2, const float* __restrict__ bl,
    u16* __restrict__ Ub, float* __restrict__ bb,
    int E, int Nn, int G, int F, int H, size_t total4,
    int EB, int NB, int CB)
{
    __shared__ float t[32][33];
    const int b = blockIdx.x;
    const int tid = threadIdx.x;
    const int C0 = EB + NB;
    const int W0 = C0 + CB;
    const int U0 = W0 + 256;

    if (b < EB) {
        int e = b * 256 + tid;
        if (e < E) {
            int d = dst[e];
            atomicAdd(&deg[d], ew[e]);
            atomicAdd(&cnt[d], 1);
        }
    } else if (b < C0) {
        int i = (b - EB) * 256 + tid;
        if (i < Nn) {
            int bt = batch[i];
            int prev = (i == 0) ? -1 : batch[i - 1];
            for (int g = prev + 1; g <= bt; ++g) gstart[g] = i;
            if (i == Nn - 1)
                for (int g = bt + 1; g <= G; ++g) gstart[g] = Nn;
        }
    } else if (b < W0) {
        size_t i = (size_t)(b - C0) * 256 + tid;
        if (i < total4) {
            const float4 v = *(const float4*)(x + i * 4);
            ushort4 o;
            o.x = f2bf(v.x); o.y = f2bf(v.y); o.z = f2bf(v.z); o.w = f2bf(v.w);
            *(ushort4*)(xb + i * 4) = o;
        }
    } else if (b < U0) {
        const int wb = b - W0;
        const int nb32 = (wb & 15) * 32, kb32 = (wb >> 4) * 32;
        const int tx = tid & 31;
        const int ty = tid >> 5;
#pragma unroll
        for (int i = 0; i < 32; i += 8)
            t[ty + i][tx] = W1[(size_t)(kb32 + ty + i) * H + nb32 + tx];
        __syncthreads();
#pragma unroll
        for (int i = 0; i < 32; i += 8)
            Wt1[(size_t)(nb32 + ty + i) * F + kb32 + tx] = f2bf(t[tx][ty + i]);
    } else {
        const int ub = b - U0;
        const int k = ub * 32 + (tid >> 3);
        const int o = tid & 7;
        float acc = 0.f;
        for (int j = 0; j < H; ++j)
            acc = fmaf(W2[(size_t)k * H + j], Wl[j * 8 + o], acc);
        Ub[(size_t)k * 8 + o] = f2bf(acc);
        if (ub == 0 && tid < 8) {
            float s = bl[tid];
            for (int j = 0; j < H; ++j)
                s = fmaf(b2[j], Wl[j * 8 + tid], s);
            bb[tid] = s;
        }
    }
}

// ---------------------------------------------------------------------------
// K2: dinv | scan_block  (1024 threads). Blocks [0,nb) scan cnt->rowptr,bsum;
// blocks [nb, nb+db) compute dinv in-place on deg.
// ---------------------------------------------------------------------------
#define SCAN_BS 1024
__global__ __launch_bounds__(1024) void scan_dinv_kernel(
    const int* __restrict__ cnt, int* __restrict__ rowptr, int* __restrict__ bsum,
    float* __restrict__ deg, int Nn, int nb)
{
    __shared__ int tmp[SCAN_BS];
    const int tid = threadIdx.x;
    if ((int)blockIdx.x < nb) {
        const int idx = blockIdx.x * SCAN_BS + tid;
        const int v = (idx < Nn) ? cnt[idx] : 0;
        tmp[tid] = v;
        __syncthreads();
        for (int off = 1; off < SCAN_BS; off <<= 1) {
            int y = (tid >= off) ? tmp[tid - off] : 0;
            __syncthreads();
            if (tid >= off) tmp[tid] += y;
            __syncthreads();
        }
        if (idx < Nn) rowptr[idx] = tmp[tid] - v;
        if (tid == SCAN_BS - 1) bsum[blockIdx.x] = tmp[tid];
    } else {
        const int i = (blockIdx.x - nb) * SCAN_BS + tid;
        if (i < Nn) deg[i] = rsqrtf(deg[i] + 1.0f);
    }
}

// K3: scan of 49 block sums (64 threads, 1 block)
__global__ void scan_sums_kernel(const int* __restrict__ bsum, int* __restrict__ boff,
                                 int nb, int* __restrict__ rowptr2, int Nn, int total)
{
    const int tid = threadIdx.x;
    const int orig = (tid < nb) ? bsum[tid] : 0;
    int v = orig;
    for (int off = 1; off < 64; off <<= 1) {
        int y = __shfl_up(v, off);
        if (tid >= off) v += y;
    }
    if (tid < nb) boff[tid] = v - orig;
    if (tid == 0) rowptr2[Nn] = total;
}

// ---------------------------------------------------------------------------
// K4: fill_csr (with on-the-fly boff) | rowptr finalize into rowptr2.
// ---------------------------------------------------------------------------
__global__ __launch_bounds__(256) void fill_final_kernel(
    const int* __restrict__ src, const int* __restrict__ dst,
    const float* __restrict__ ew, const float* __restrict__ dinv,
    const int* __restrict__ rowptr, const int* __restrict__ boff,
    int* __restrict__ cur, int* __restrict__ csr_src, float* __restrict__ csr_norm,
    int* __restrict__ rowptr2, int E, int Nn, int EB)
{
    const int b = blockIdx.x;
    const int tid = threadIdx.x;
    if (b < EB) {
        int e = b * 256 + tid;
        if (e >= E) return;
        int s = src[e];
        int d = dst[e];
        float nrm = dinv[s] * ew[e] * dinv[d];
        int p = rowptr[d] + boff[d >> 10] + atomicAdd(&cur[d], 1);
        csr_src[p] = s;
        csr_norm[p] = nrm;
    } else {
        int i = (b - EB) * 256 + tid;
        if (i < Nn) rowptr2[i] = rowptr[i] + boff[i >> 10];
    }
}

// ---------------------------------------------------------------------------
// AGG1 fused: per node n (one block, 128 threads, 4 cols/thread):
//   h = relu(b1 + dinv^2*T1[n] + sum norm*T1[src])      (fp32, in regs)
//   Y[n][o] = sum_c h[c]*U[c][o]                        (thread-local rows)
// ---------------------------------------------------------------------------
__global__ __launch_bounds__(128) void agg_proj_kernel(
    const u16* __restrict__ hw, const float* __restrict__ dinv,
    const int* __restrict__ rowptr, const int* __restrict__ csr_src,
    const float* __restrict__ csr_norm, const float* __restrict__ bias,
    const u16* __restrict__ Ub, float* __restrict__ Y)
{
    const int n = blockIdx.x;
    const int c = threadIdx.x * 4;
    const float di = dinv[n];
    float4 acc = *(const float4*)(bias + c);
    {
        const float s = di * di;
        const ushort4 hv = *(const ushort4*)(hw + (size_t)n * 512 + c);
        acc.x = fmaf(s, bf2f(hv.x), acc.x);
        acc.y = fmaf(s, bf2f(hv.y), acc.y);
        acc.z = fmaf(s, bf2f(hv.z), acc.z);
        acc.w = fmaf(s, bf2f(hv.w), acc.w);
    }
    const int beg = rowptr[n];
    const int end = rowptr[n + 1];
    for (int i = beg; i < end; ++i) {
        const int s = csr_src[i];
        const float nr = csr_norm[i];
        const ushort4 v = *(const ushort4*)(hw + (size_t)s * 512 + c);
        acc.x = fmaf(nr, bf2f(v.x), acc.x);
        acc.y = fmaf(nr, bf2f(v.y), acc.y);
        acc.z = fmaf(nr, bf2f(v.z), acc.z);
        acc.w = fmaf(nr, bf2f(v.w), acc.w);
    }
    acc.x = fmaxf(acc.x, 0.f);
    acc.y = fmaxf(acc.y, 0.f);
    acc.z = fmaxf(acc.z, 0.f);
    acc.w = fmaxf(acc.w, 0.f);

    // project: rows c..c+3 of Ub (bf16 [512][8]) belong to this thread only
    float part[8];
    {
        const s16x8 u0 = *(const s16x8*)(Ub + (size_t)(c + 0) * 8);
        const s16x8 u1 = *(const s16x8*)(Ub + (size_t)(c + 1) * 8);
        const s16x8 u2 = *(const s16x8*)(Ub + (size_t)(c + 2) * 8);
        const s16x8 u3 = *(const s16x8*)(Ub + (size_t)(c + 3) * 8);
#pragma unroll
        for (int o = 0; o < 8; ++o) {
            float p = acc.x * bf2f((u16)u0[o]);
            p = fmaf(acc.y, bf2f((u16)u1[o]), p);
            p = fmaf(acc.z, bf2f((u16)u2[o]), p);
            p = fmaf(acc.w, bf2f((u16)u3[o]), p);
            part[o] = p;
        }
    }
#pragma unroll
    for (int o = 0; o < 8; ++o) {
#pragma unroll
        for (int off = 1; off < 64; off <<= 1)
            part[o] += __shfl_xor(part[o], off);
    }
    __shared__ float red[2][8];
    const int lane = threadIdx.x & 63;
    const int wid = threadIdx.x >> 6;
    if (lane == 0)
#pragma unroll
        for (int o = 0; o < 8; ++o) red[wid][o] = part[o];
    __syncthreads();
    if (threadIdx.x < 8)
        Y[(size_t)n * 8 + threadIdx.x] = red[0][threadIdx.x] + red[1][threadIdx.x];
}

// ---------------------------------------------------------------------------
// mini-agg on 8 cols: Z[n][o] = dinv^2*Y[n][o] + sum norm*Y[src][o]
// ---------------------------------------------------------------------------
__global__ __launch_bounds__(256) void mini_agg_kernel(
    const float* __restrict__ Y, const float* __restrict__ dinv,
    const int* __restrict__ rowptr, const int* __restrict__ csr_src,
    const float* __restrict__ csr_norm, float* __restrict__ Z, int Nn)
{
    const int t = threadIdx.x;
    const int n = blockIdx.x * 32 + (t >> 3);
    const int o = t & 7;
    if (n >= Nn) return;
    const float di = dinv[n];
    float acc = di * di * Y[(size_t)n * 8 + o];
    const int beg = rowptr[n];
    const int end = rowptr[n + 1];
    for (int i = beg; i < end; ++i)
        acc = fmaf(csr_norm[i], Y[(size_t)csr_src[i] * 8 + o], acc);
    Z[(size_t)n * 8 + o] = acc;
}

// ---------------------------------------------------------------------------
// per-graph mean pool + bias (no atomics)
// ---------------------------------------------------------------------------
__global__ __launch_bounds__(256) void pool8_kernel(
    const float* __restrict__ Z, const int* __restrict__ gstart,
    const float* __restrict__ bb, float* __restrict__ out)
{
    const int g = blockIdx.x;
    const int t = threadIdx.x;
    const int grp = t >> 3;
    const int o = t & 7;
    const int beg = gstart[g], end = gstart[g + 1];
    float acc = 0.f;
    for (int n = beg + grp; n < end; n += 32)
        acc += Z[(size_t)n * 8 + o];
    acc += __shfl_xor(acc, 8);
    acc += __shfl_xor(acc, 16);
    acc += __shfl_xor(acc, 32);
    __shared__ float red[4][8];
    const int lane = t & 63;
    const int wid = t >> 6;
    if (lane < 8) red[wid][lane] = acc;
    __syncthreads();
    if (t < 8) {
        const int c = end - beg;
        const float inv = 1.0f / (float)(c > 0 ? c : 1);
        out[g * 8 + t] = (red[0][t] + red[1][t] + red[2][t] + red[3][t]) * inv + bb[t];
    }
}

// ---------------------------------------------------------------------------
extern "C" void kernel_launch(void* const* d_in, const int* in_sizes, int n_in,
                              void* d_out, int out_size, void* d_ws, size_t ws_size,
                              hipStream_t stream)
{
    const float* x    = (const float*)d_in[0];
    const int*   eidx = (const int*)d_in[1];
    const int*   batch= (const int*)d_in[2];
    const float* ew   = (const float*)d_in[3];
    const float* W1   = (const float*)d_in[4];
    const float* b1   = (const float*)d_in[5];
    const float* W2   = (const float*)d_in[6];
    const float* b2   = (const float*)d_in[7];
    const float* Wl   = (const float*)d_in[8];
    const float* bl   = (const float*)d_in[9];
    float* out = (float*)d_out;

    const int Nn = in_sizes[2];            // 50000
    const int Ee = in_sizes[3];            // 800000
    const int F  = in_sizes[0] / Nn;       // 512
    const int H  = in_sizes[5];            // 512
    const int G  = 64;
    const int Mpad = (Nn + BM - 1) / BM * BM;

    const int* src = eidx;
    const int* dst = eidx + Ee;

    char* base = (char*)d_ws;
    size_t off = 0;
    auto alloc = [&](size_t bytes) -> char* {
        char* p = base + off;
        off += (bytes + 255) & ~(size_t)255;
        return p;
    };
    u16* xb  = (u16*)alloc((size_t)Mpad * F * sizeof(u16));
    u16* hb0 = (u16*)alloc((size_t)Mpad * H * sizeof(u16));   // T1 = x@W1
    u16* Wt1 = (u16*)alloc((size_t)F * H * sizeof(u16));
    u16* Ub  = (u16*)alloc((size_t)H * 8 * sizeof(u16));
    float* Yb = (float*)alloc((size_t)Nn * 8 * sizeof(float));
    float* Zb = (float*)alloc((size_t)Nn * 8 * sizeof(float));
    float* bb = (float*)alloc(8 * sizeof(float));
    char* zero_begin = base + off;
    float* deg  = (float*)alloc((size_t)Nn * sizeof(float));  // becomes dinv
    int*   cnt  = (int*)alloc((size_t)Nn * sizeof(int));
    int*   cur  = (int*)alloc((size_t)Nn * sizeof(int));
    char* zero_end = base + off;
    int*   gstart   = (int*)alloc((size_t)(G + 1) * sizeof(int));
    int*   rowptr   = (int*)alloc((size_t)(Nn + 1) * sizeof(int));   // partial
    int*   rowptr2  = (int*)alloc((size_t)(Nn + 1) * sizeof(int));   // final
    int*   bsum     = (int*)alloc(64 * sizeof(int));
    int*   boff     = (int*)alloc(64 * sizeof(int));
    int*   csr_src  = (int*)alloc((size_t)Ee * sizeof(int));
    float* csr_norm = (float*)alloc((size_t)Ee * sizeof(float));
    (void)ws_size;

    hipMemsetAsync(zero_begin, 0, (size_t)(zero_end - zero_begin), stream);

    const size_t total4 = (size_t)Nn * F / 4;
    const int EB = (Ee + 255) / 256;                 // 3125
    const int NB = (Nn + 255) / 256;                 // 196
    const int CB = (int)((total4 + 255) / 256);      // 25000
    const int K1_blocks = EB + NB + CB + 256 + (H / 32);
    prep_kernel<<<K1_blocks, 256, 0, stream>>>(
        dst, ew, deg, cnt, batch, gstart, x, xb, W1, Wt1,
        W2, Wl, b2, bl, Ub, bb, Ee, Nn, G, F, H, total4, EB, NB, CB);

    const int nb = (Nn + SCAN_BS - 1) / SCAN_BS;     // 49
    const int db = (Nn + SCAN_BS - 1) / SCAN_BS;
    scan_dinv_kernel<<<nb + db, SCAN_BS, 0, stream>>>(cnt, rowptr, bsum, deg, Nn, nb);
    scan_sums_kernel<<<1, 64, 0, stream>>>(bsum, boff, nb, rowptr2, Nn, Ee);
    fill_final_kernel<<<EB + NB, 256, 0, stream>>>(src, dst, ew, deg, rowptr, boff,
                                                   cur, csr_src, csr_norm, rowptr2,
                                                   Ee, Nn, EB);

    dim3 ggrid(H / BN, Mpad / BM);
    gemm_bf16_kernel<<<ggrid, 256, 0, stream>>>(xb, Wt1, hb0, Nn, H, F);
    agg_proj_kernel<<<Nn, 128, 0, stream>>>(hb0, deg, rowptr2, csr_src, csr_norm,
                                            b1, Ub, Yb);
    mini_agg_kernel<<<(Nn + 31) / 32, 256, 0, stream>>>(Yb, deg, rowptr2, csr_src,
                                                        csr_norm, Zb, Nn);
    pool8_kernel<<<G, 256, 0, stream>>>(Zb, gstart, bb, out);
}

// Round 6
// 364.763 us; speedup vs baseline: 2.1378x; 1.3238x over previous
//
#include <hip/hip_runtime.h>
#include <cstddef>
#include <cstdint>

// ---------------------------------------------------------------------------
// GCN pipeline, fused + atomic-lean:
//   out = P @ A_hat @ (relu(A_hat@(X@W1)+b1) @ U) + bb,  U=W2@Wl, bb=b2@Wl+bl
// Dispatches (8):
//   memset(packed 400KB) ->
//   K1{hist(64b packed atomic, ord=return)|convert_x striped 1:7|gstart|wtrans|u} ->
//   K2{scan cnt | dinv} -> K3{scan_sums} ->
//   K4{GEMM1 (bf16 MFMA, 128x256) | fill_csr (NO atomics) | rowptr2} ->
//   AGG1+relu+proj8 -> mini_agg -> pool8
// Rules learned:
//  R3: same-address cross-XCD atomics ~300ns each — avoid funnels.
//  R4: prep-chain dispatches are ~half the runtime — fuse independent work.
//  R5: EVERY device-scope atomic is a fabric transaction (~8 Gops/s ceiling,
//      shows up as WRITE_SIZE inflation). Pack multiple counters into one
//      64-bit atomic; use its return value to pre-assign CSR slots.
// ---------------------------------------------------------------------------

typedef unsigned short u16;
typedef unsigned long long u64;
typedef short s16x8 __attribute__((ext_vector_type(8)));
typedef float f32x4 __attribute__((ext_vector_type(4)));

__device__ __forceinline__ float bf2f(u16 h) {
    union { unsigned int u; float f; } c; c.u = ((unsigned int)h) << 16; return c.f;
}
__device__ __forceinline__ u16 f2bf(float f) {
    union { float f; unsigned int u; } c; c.f = f;
    unsigned int u = c.u;
    u += 0x7FFFu + ((u >> 16) & 1u);   // round-to-nearest-even
    return (u16)(u >> 16);
}

#define GLD_LDS16(g, l) __builtin_amdgcn_global_load_lds( \
    (const __attribute__((address_space(1))) unsigned int*)(const void*)(g), \
    (__attribute__((address_space(3))) unsigned int*)(void*)(l), 16, 0, 0)

#define BM 128
#define BN 256
#define BKK 32
#define DEG_MASK ((1ull << 40) - 1)

// ---------------------------------------------------------------------------
// K1: fused prep. Block roles:
//   [0,MIX):  (b&7)==7 -> histogram block (one 64b atomic per edge, store ord)
//             else     -> convert_x block (fp32 -> bf16)
//   [MIX,MIX+NB):    gstart (sorted-batch boundaries)
//   [+256):          wtrans W1 -> Wt1 (bf16, transposed)
//   [+16):           U = W2@Wl (bf16), bb = b2@Wl + bl
// ---------------------------------------------------------------------------
__global__ __launch_bounds__(256) void prep_kernel(
    const int* __restrict__ dst, const float* __restrict__ ew,
    u64* __restrict__ packed, unsigned int* __restrict__ ord,
    const int* __restrict__ batch, int* __restrict__ gstart,
    const float* __restrict__ x, u16* __restrict__ xb,
    const float* __restrict__ W1, u16* __restrict__ Wt1,
    const float* __restrict__ W2, const float* __restrict__ Wl,
    const float* __restrict__ b2, const float* __restrict__ bl,
    u16* __restrict__ Ub, float* __restrict__ bb,
    int E, int Nn, int G, int F, int H, size_t total4,
    int MIX, int NB)
{
    __shared__ float t[32][33];
    const int b = blockIdx.x;
    const int tid = threadIdx.x;

    if (b < MIX) {
        if ((b & 7) == 7) {
            int e = (b >> 3) * 256 + tid;
            if (e < E) {
                int d = dst[e];
                u64 pk = (1ull << 40) | (u64)(ew[e] * 1048576.0f + 0.5f);
                u64 old = atomicAdd(&packed[d], pk);
                ord[e] = (unsigned int)(old >> 40);
            }
        } else {
            size_t i = (size_t)(b - (b >> 3)) * 256 + tid;
            if (i < total4) {
                const float4 v = *(const float4*)(x + i * 4);
                ushort4 o;
                o.x = f2bf(v.x); o.y = f2bf(v.y); o.z = f2bf(v.z); o.w = f2bf(v.w);
                *(ushort4*)(xb + i * 4) = o;
            }
        }
    } else if (b < MIX + NB) {
        int i = (b - MIX) * 256 + tid;
        if (i < Nn) {
            int bt = batch[i];
            int prev = (i == 0) ? -1 : batch[i - 1];
            for (int g = prev + 1; g <= bt; ++g) gstart[g] = i;
            if (i == Nn - 1)
                for (int g = bt + 1; g <= G; ++g) gstart[g] = Nn;
        }
    } else if (b < MIX + NB + 256) {
        const int wb = b - MIX - NB;
        const int nb32 = (wb & 15) * 32, kb32 = (wb >> 4) * 32;
        const int tx = tid & 31;
        const int ty = tid >> 5;
#pragma unroll
        for (int i = 0; i < 32; i += 8)
            t[ty + i][tx] = W1[(size_t)(kb32 + ty + i) * H + nb32 + tx];
        __syncthreads();
#pragma unroll
        for (int i = 0; i < 32; i += 8)
            Wt1[(size_t)(nb32 + ty + i) * F + kb32 + tx] = f2bf(t[tx][ty + i]);
    } else {
        const int ub = b - MIX - NB - 256;
        const int k = ub * 32 + (tid >> 3);
        const int o = tid & 7;
        float acc = 0.f;
        for (int j = 0; j < H; ++j)
            acc = fmaf(W2[(size_t)k * H + j], Wl[j * 8 + o], acc);
        Ub[(size_t)k * 8 + o] = f2bf(acc);
        if (ub == 0 && tid < 8) {
            float s = bl[tid];
            for (int j = 0; j < H; ++j)
                s = fmaf(b2[j], Wl[j * 8 + tid], s);
            bb[tid] = s;
        }
    }
}

// ---------------------------------------------------------------------------
// K2: blocks [0,nb) scan cnt(=packed>>40) -> rowptr,bsum; [nb,..) dinv in-place
// ---------------------------------------------------------------------------
#define SCAN_BS 1024
__global__ __launch_bounds__(1024) void scan_dinv_kernel(
    const u64* __restrict__ packed, int* __restrict__ rowptr, int* __restrict__ bsum,
    float* __restrict__ dinv, int Nn, int nb)
{
    __shared__ int tmp[SCAN_BS];
    const int tid = threadIdx.x;
    if ((int)blockIdx.x < nb) {
        const int idx = blockIdx.x * SCAN_BS + tid;
        const int v = (idx < Nn) ? (int)(packed[idx] >> 40) : 0;
        tmp[tid] = v;
        __syncthreads();
        for (int off = 1; off < SCAN_BS; off <<= 1) {
            int y = (tid >= off) ? tmp[tid - off] : 0;
            __syncthreads();
            if (tid >= off) tmp[tid] += y;
            __syncthreads();
        }
        if (idx < Nn) rowptr[idx] = tmp[tid] - v;
        if (tid == SCAN_BS - 1) bsum[blockIdx.x] = tmp[tid];
    } else {
        const int i = (blockIdx.x - nb) * SCAN_BS + tid;
        if (i < Nn) {
            float deg = (float)(packed[i] & DEG_MASK) * (1.0f / 1048576.0f);
            dinv[i] = rsqrtf(deg + 1.0f);
        }
    }
}

// K3: scan of block sums (64 threads, 1 block); writes rowptr2[Nn]=E
__global__ void scan_sums_kernel(const int* __restrict__ bsum, int* __restrict__ boff,
                                 int nb, int* __restrict__ rowptr2, int Nn, int total)
{
    const int tid = threadIdx.x;
    const int orig = (tid < nb) ? bsum[tid] : 0;
    int v = orig;
    for (int off = 1; off < 64; off <<= 1) {
        int y = __shfl_up(v, off);
        if (tid >= off) v += y;
    }
    if (tid < nb) boff[tid] = v - orig;
    if (tid == 0) rowptr2[Nn] = total;
}

// ---------------------------------------------------------------------------
// K4: GEMM1 | fill_csr (no atomics, slot = rowptr+boff+ord) | rowptr2 finalize
// GEMM: C[M,N]=A[M,K]@B[K,N]; Bt=B^T [N][K] bf16; C bf16. 128x256 tile, 4 waves.
// ---------------------------------------------------------------------------
__global__ __launch_bounds__(256) void gemm_fill_kernel(
    const u16* __restrict__ A, const u16* __restrict__ Bt, u16* __restrict__ C,
    int M, int N, int K, int GB, int gx,
    const int* __restrict__ src, const int* __restrict__ dst,
    const float* __restrict__ ew, const unsigned int* __restrict__ ord,
    const float* __restrict__ dinv, const int* __restrict__ rowptr,
    const int* __restrict__ boff, int2* __restrict__ csr,
    int* __restrict__ rowptr2, int E, int Nn, int EB)
{
    __shared__ u16 As[BM * BKK];   // 8 KB
    __shared__ u16 Bs[BN * BKK];   // 16 KB
    const int b = blockIdx.x;
    const int tid = threadIdx.x;

    if (b < GB) {
        const int lane = tid & 63;
        const int wave = tid >> 6;
        const int wr = wave >> 1, wc = wave & 1;
        const int m0 = (b / gx) * BM;
        const int n0 = (b % gx) * BN;

        const int srow = tid >> 2;
        const int scol = (tid & 3) * 8;

        f32x4 acc[4][8] = {};

        const u16* aptr0 = A + (size_t)(m0 + srow) * K + scol;
        const u16* aptr1 = A + (size_t)(m0 + srow + 64) * K + scol;
        const u16* bptr0 = Bt + (size_t)(n0 + srow) * K + scol;
        const u16* bptr1 = Bt + (size_t)(n0 + srow + 64) * K + scol;
        const u16* bptr2 = Bt + (size_t)(n0 + srow + 128) * K + scol;
        const u16* bptr3 = Bt + (size_t)(n0 + srow + 192) * K + scol;

        for (int k0 = 0; k0 < K; k0 += BKK) {
            GLD_LDS16(aptr0 + k0, As + (size_t)tid * 8);
            GLD_LDS16(aptr1 + k0, As + (size_t)(256 + tid) * 8);
            GLD_LDS16(bptr0 + k0, Bs + (size_t)tid * 8);
            GLD_LDS16(bptr1 + k0, Bs + (size_t)(256 + tid) * 8);
            GLD_LDS16(bptr2 + k0, Bs + (size_t)(512 + tid) * 8);
            GLD_LDS16(bptr3 + k0, Bs + (size_t)(768 + tid) * 8);
            __syncthreads();

            s16x8 af[4], bfr[8];
#pragma unroll
            for (int mi = 0; mi < 4; ++mi)
                af[mi] = *(const s16x8*)(As + (wr * 64 + mi * 16 + (lane & 15)) * BKK + (lane >> 4) * 8);
#pragma unroll
            for (int nj = 0; nj < 8; ++nj)
                bfr[nj] = *(const s16x8*)(Bs + (wc * 128 + nj * 16 + (lane & 15)) * BKK + (lane >> 4) * 8);
#pragma unroll
            for (int mi = 0; mi < 4; ++mi)
#pragma unroll
                for (int nj = 0; nj < 8; ++nj)
                    acc[mi][nj] = __builtin_amdgcn_mfma_f32_16x16x32_bf16(af[mi], bfr[nj], acc[mi][nj], 0, 0, 0);
            __syncthreads();
        }

        const int crow = (lane >> 4) * 4;
        const int ccol = lane & 15;
#pragma unroll
        for (int mi = 0; mi < 4; ++mi) {
            const int gr0 = m0 + wr * 64 + mi * 16 + crow;
#pragma unroll
            for (int r = 0; r < 4; ++r) {
                const int gr = gr0 + r;
                if (gr < M) {
#pragma unroll
                    for (int nj = 0; nj < 8; ++nj)
                        C[(size_t)gr * N + n0 + wc * 128 + nj * 16 + ccol] = f2bf(acc[mi][nj][r]);
                }
            }
        }
    } else if (b < GB + EB) {
        int e = (b - GB) * 256 + tid;
        if (e < E) {
            int s = src[e];
            int d = dst[e];
            float nrm = dinv[s] * ew[e] * dinv[d];
            int p = rowptr[d] + boff[d >> 10] + (int)ord[e];
            csr[p] = make_int2(s, __float_as_int(nrm));
        }
    } else {
        int i = (b - GB - EB) * 256 + tid;
        if (i < Nn) rowptr2[i] = rowptr[i] + boff[i >> 10];
    }
}

// ---------------------------------------------------------------------------
// AGG1 fused: per node n (128 threads, 4 cols each):
//   h = relu(b1 + dinv^2*T1[n] + sum norm*T1[src])   (fp32, regs)
//   Y[n][o] = sum_c h[c]*U[c][o]
// ---------------------------------------------------------------------------
__global__ __launch_bounds__(128) void agg_proj_kernel(
    const u16* __restrict__ hw, const float* __restrict__ dinv,
    const int* __restrict__ rowptr, const int2* __restrict__ csr,
    const float* __restrict__ bias, const u16* __restrict__ Ub,
    float* __restrict__ Y)
{
    const int n = blockIdx.x;
    const int c = threadIdx.x * 4;
    const float di = dinv[n];
    float4 acc = *(const float4*)(bias + c);
    {
        const float s = di * di;
        const ushort4 hv = *(const ushort4*)(hw + (size_t)n * 512 + c);
        acc.x = fmaf(s, bf2f(hv.x), acc.x);
        acc.y = fmaf(s, bf2f(hv.y), acc.y);
        acc.z = fmaf(s, bf2f(hv.z), acc.z);
        acc.w = fmaf(s, bf2f(hv.w), acc.w);
    }
    const int beg = rowptr[n];
    const int end = rowptr[n + 1];
    for (int i = beg; i < end; ++i) {
        const int2 en = csr[i];
        const float nr = __int_as_float(en.y);
        const ushort4 v = *(const ushort4*)(hw + (size_t)en.x * 512 + c);
        acc.x = fmaf(nr, bf2f(v.x), acc.x);
        acc.y = fmaf(nr, bf2f(v.y), acc.y);
        acc.z = fmaf(nr, bf2f(v.z), acc.z);
        acc.w = fmaf(nr, bf2f(v.w), acc.w);
    }
    acc.x = fmaxf(acc.x, 0.f);
    acc.y = fmaxf(acc.y, 0.f);
    acc.z = fmaxf(acc.z, 0.f);
    acc.w = fmaxf(acc.w, 0.f);

    float part[8];
    {
        const s16x8 u0 = *(const s16x8*)(Ub + (size_t)(c + 0) * 8);
        const s16x8 u1 = *(const s16x8*)(Ub + (size_t)(c + 1) * 8);
        const s16x8 u2 = *(const s16x8*)(Ub + (size_t)(c + 2) * 8);
        const s16x8 u3 = *(const s16x8*)(Ub + (size_t)(c + 3) * 8);
#pragma unroll
        for (int o = 0; o < 8; ++o) {
            float p = acc.x * bf2f((u16)u0[o]);
            p = fmaf(acc.y, bf2f((u16)u1[o]), p);
            p = fmaf(acc.z, bf2f((u16)u2[o]), p);
            p = fmaf(acc.w, bf2f((u16)u3[o]), p);
            part[o] = p;
        }
    }
#pragma unroll
    for (int o = 0; o < 8; ++o) {
#pragma unroll
        for (int off = 1; off < 64; off <<= 1)
            part[o] += __shfl_xor(part[o], off);
    }
    __shared__ float red[2][8];
    const int lane = threadIdx.x & 63;
    const int wid = threadIdx.x >> 6;
    if (lane == 0)
#pragma unroll
        for (int o = 0; o < 8; ++o) red[wid][o] = part[o];
    __syncthreads();
    if (threadIdx.x < 8)
        Y[(size_t)n * 8 + threadIdx.x] = red[0][threadIdx.x] + red[1][threadIdx.x];
}

// ---------------------------------------------------------------------------
// mini-agg on 8 cols: Z[n][o] = dinv^2*Y[n][o] + sum norm*Y[src][o]
// ---------------------------------------------------------------------------
__global__ __launch_bounds__(256) void mini_agg_kernel(
    const float* __restrict__ Y, const float* __restrict__ dinv,
    const int* __restrict__ rowptr, const int2* __restrict__ csr,
    float* __restrict__ Z, int Nn)
{
    const int t = threadIdx.x;
    const int n = blockIdx.x * 32 + (t >> 3);
    const int o = t & 7;
    if (n >= Nn) return;
    const float di = dinv[n];
    float acc = di * di * Y[(size_t)n * 8 + o];
    const int beg = rowptr[n];
    const int end = rowptr[n + 1];
    for (int i = beg; i < end; ++i) {
        const int2 en = csr[i];
        acc = fmaf(__int_as_float(en.y), Y[(size_t)en.x * 8 + o], acc);
    }
    Z[(size_t)n * 8 + o] = acc;
}

// ---------------------------------------------------------------------------
// per-graph mean pool + bias (no atomics)
// ---------------------------------------------------------------------------
__global__ __launch_bounds__(256) void pool8_kernel(
    const float* __restrict__ Z, const int* __restrict__ gstart,
    const float* __restrict__ bb, float* __restrict__ out)
{
    const int g = blockIdx.x;
    const int t = threadIdx.x;
    const int grp = t >> 3;
    const int o = t & 7;
    const int beg = gstart[g], end = gstart[g + 1];
    float acc = 0.f;
    for (int n = beg + grp; n < end; n += 32)
        acc += Z[(size_t)n * 8 + o];
    acc += __shfl_xor(acc, 8);
    acc += __shfl_xor(acc, 16);
    acc += __shfl_xor(acc, 32);
    __shared__ float red[4][8];
    const int lane = t & 63;
    const int wid = t >> 6;
    if (lane < 8) red[wid][lane] = acc;
    __syncthreads();
    if (t < 8) {
        const int c = end - beg;
        const float inv = 1.0f / (float)(c > 0 ? c : 1);
        out[g * 8 + t] = (red[0][t] + red[1][t] + red[2][t] + red[3][t]) * inv + bb[t];
    }
}

// ---------------------------------------------------------------------------
extern "C" void kernel_launch(void* const* d_in, const int* in_sizes, int n_in,
                              void* d_out, int out_size, void* d_ws, size_t ws_size,
                              hipStream_t stream)
{
    const float* x    = (const float*)d_in[0];
    const int*   eidx = (const int*)d_in[1];
    const int*   batch= (const int*)d_in[2];
    const float* ew   = (const float*)d_in[3];
    const float* W1   = (const float*)d_in[4];
    const float* b1   = (const float*)d_in[5];
    const float* W2   = (const float*)d_in[6];
    const float* b2   = (const float*)d_in[7];
    const float* Wl   = (const float*)d_in[8];
    const float* bl   = (const float*)d_in[9];
    float* out = (float*)d_out;

    const int Nn = in_sizes[2];            // 50000
    const int Ee = in_sizes[3];            // 800000
    const int F  = in_sizes[0] / Nn;       // 512
    const int H  = in_sizes[5];            // 512
    const int G  = 64;
    const int Mpad = (Nn + BM - 1) / BM * BM;

    const int* src = eidx;
    const int* dst = eidx + Ee;

    char* base = (char*)d_ws;
    size_t off = 0;
    auto alloc = [&](size_t bytes) -> char* {
        char* p = base + off;
        off += (bytes + 255) & ~(size_t)255;
        return p;
    };
    u16* xb  = (u16*)alloc((size_t)Mpad * F * sizeof(u16));
    u16* hb0 = (u16*)alloc((size_t)Mpad * H * sizeof(u16));   // T1 = x@W1
    u16* Wt1 = (u16*)alloc((size_t)F * H * sizeof(u16));
    u16* Ub  = (u16*)alloc((size_t)H * 8 * sizeof(u16));
    float* Yb = (float*)alloc((size_t)Nn * 8 * sizeof(float));
    float* Zb = (float*)alloc((size_t)Nn * 8 * sizeof(float));
    float* bb = (float*)alloc(8 * sizeof(float));
    char* zero_begin = base + off;
    u64*  packed = (u64*)alloc((size_t)Nn * sizeof(u64));     // cnt<<40 | deg_fix
    char* zero_end = base + off;
    unsigned int* ord = (unsigned int*)alloc((size_t)Ee * sizeof(unsigned int));
    float* dinv = (float*)alloc((size_t)Nn * sizeof(float));
    int*   gstart   = (int*)alloc((size_t)(G + 1) * sizeof(int));
    int*   rowptr   = (int*)alloc((size_t)(Nn + 1) * sizeof(int));   // partial
    int*   rowptr2  = (int*)alloc((size_t)(Nn + 1) * sizeof(int));   // final
    int*   bsum     = (int*)alloc(64 * sizeof(int));
    int*   boff     = (int*)alloc(64 * sizeof(int));
    int2*  csr      = (int2*)alloc((size_t)Ee * sizeof(int2));
    (void)ws_size;

    hipMemsetAsync(zero_begin, 0, (size_t)(zero_end - zero_begin), stream);

    const size_t total4 = (size_t)Nn * F / 4;
    const int EB = (Ee + 255) / 256;                 // 3125 histogram blocks
    const int NB = (Nn + 255) / 256;                 // 196
    const int CB = (int)((total4 + 255) / 256);      // 25000 convert blocks
    // striped mix region: (b&7)==7 -> hist (b>>3), else convert (b - (b>>3))
    int MIX = 8 * EB;
    if (MIX < (CB * 8 + 6) / 7) MIX = (CB * 8 + 6) / 7;
    const int K1_blocks = MIX + NB + 256 + (H / 32);
    prep_kernel<<<K1_blocks, 256, 0, stream>>>(
        dst, ew, packed, ord, batch, gstart, x, xb, W1, Wt1,
        W2, Wl, b2, bl, Ub, bb, Ee, Nn, G, F, H, total4, MIX, NB);

    const int nb = (Nn + SCAN_BS - 1) / SCAN_BS;     // 49
    scan_dinv_kernel<<<nb + nb, SCAN_BS, 0, stream>>>(packed, rowptr, bsum, dinv, Nn, nb);
    scan_sums_kernel<<<1, 64, 0, stream>>>(bsum, boff, nb, rowptr2, Nn, Ee);

    const int gx = H / BN;                           // 2
    const int GB = gx * (Mpad / BM);                 // 782
    gemm_fill_kernel<<<GB + EB + NB, 256, 0, stream>>>(
        xb, Wt1, hb0, Nn, H, F, GB, gx,
        src, dst, ew, ord, dinv, rowptr, boff, csr, rowptr2, Ee, Nn, EB);

    agg_proj_kernel<<<Nn, 128, 0, stream>>>(hb0, dinv, rowptr2, csr, b1, Ub, Yb);
    mini_agg_kernel<<<(Nn + 31) / 32, 256, 0, stream>>>(Yb, dinv, rowptr2, csr, Zb, Nn);
    pool8_kernel<<<G, 256, 0, stream>>>(Zb, gstart, bb, out);
}